// Round 19
// baseline (550.703 us; speedup 1.0000x reference)
//
#include <hip/hip_runtime.h>
#include <math.h>

#define LATENT 256
#define EMBD 128
#define VOCAB 600
#define NLEV 12
#define NNODES 65536
#define NTREES 32
#define MAXM 6400            // >= count(+13 sigma); multiple of 128
#define INV_N (1.0f/65536.0f)

typedef unsigned short ushort_t;
typedef __attribute__((ext_vector_type(8))) short short8;
typedef __attribute__((ext_vector_type(4))) float float4v;
typedef __attribute__((ext_vector_type(2))) float float2v;
typedef __attribute__((ext_vector_type(8))) unsigned short u16x8;
typedef __attribute__((ext_vector_type(4))) unsigned short u16x4;

#define GLOBAL_AS __attribute__((address_space(1)))
#define LDS_AS __attribute__((address_space(3)))

__device__ __forceinline__ float sigm(float x){ return 1.0f/(1.0f+expf(-x)); }
__device__ __forceinline__ float bcef(float x, float y){
  return fmaxf(x,0.0f) - x*y + log1pf(expf(-fabsf(x)));
}
__device__ __forceinline__ ushort_t f2bf(float f){
  union{float f; unsigned u;} v; v.f=f;
  unsigned r = v.u + 0x7fffu + ((v.u>>16)&1u);
  return (ushort_t)(r>>16);
}
__device__ __forceinline__ float bf2f(ushort_t u){
  union{unsigned u; float f;} v; v.u = ((unsigned)u)<<16; return v.f;
}

__device__ __forceinline__ void gload_lds(const void* src, void* dst){
  __builtin_amdgcn_global_load_lds((const GLOBAL_AS void*)src, (LDS_AS void*)dst, 16, 0, 0);
}

__device__ __forceinline__ void acc_zero4(float4v acc[4][4]){
  #pragma unroll
  for (int i=0;i<4;i++){
    #pragma unroll
    for (int j=0;j<4;j++){ acc[i][j] = (float4v){0.f,0.f,0.f,0.f}; }
  }
}
__device__ __forceinline__ void acc_zero42(float4v acc[4][2]){
  #pragma unroll
  for (int i=0;i<4;i++){
    #pragma unroll
    for (int j=0;j<2;j++){ acc[i][j] = (float4v){0.f,0.f,0.f,0.f}; }
  }
}

// ---- shared GEMM pieces (m97 structure, T2 swizzle) ----
__device__ __forceinline__ void stageB128(const char* Wb, int strideB, int n0, int k0,
    int srow, int skb, char* BsB, int t){
  #pragma unroll
  for (int i=0;i<4;i++){
    int row = srow + 32*i;
    int kbs = skb ^ ((row&7)<<4);
    const char* src = Wb + (size_t)(n0+row)*strideB + k0*2 + kbs;
    gload_lds(src, BsB + i*4096 + t*16);
  }
}
// direct (compact, padded) A staging, BM=128
__device__ __forceinline__ void stageA128(const char* Ab, int strideA, int m0, int k0,
    int srow, int skb, char* AsB, int t){
  #pragma unroll
  for (int i=0;i<4;i++){
    int row = srow + 32*i;
    int kbs = skb ^ ((row&7)<<4);
    const char* src = Ab + (size_t)(m0+row)*strideA + k0*2 + kbs;
    gload_lds(src, AsB + i*4096 + t*16);
  }
}
// direct (compact, padded) A staging, BM=64 (2 passes)
__device__ __forceinline__ void stageA64(const char* Ab, int strideA, int m0, int k0,
    int srow, int skb, char* AsB, int t){
  #pragma unroll
  for (int i=0;i<2;i++){
    int row = srow + 32*i;
    int kbs = skb ^ ((row&7)<<4);
    const char* src = Ab + (size_t)(m0+row)*strideA + k0*2 + kbs;
    gload_lds(src, AsB + i*4096 + t*16);
  }
}

__device__ __forceinline__ void mfma_phase4(const char* AsB, const char* BsB,
    float4v acc[4][4], int lane, int wr, int wc){
  #pragma unroll
  for (int kk=0;kk<2;kk++){
    short8 af[4], bfr[4];
    const int kb = kk*64 + (lane>>4)*16;
    #pragma unroll
    for (int mf=0;mf<4;mf++){
      int row = wr*64 + mf*16 + (lane&15);
      af[mf] = *(const short8*)(AsB + row*128 + (kb ^ ((row&7)<<4)));
    }
    #pragma unroll
    for (int nf=0;nf<4;nf++){
      int row = wc*64 + nf*16 + (lane&15);
      bfr[nf] = *(const short8*)(BsB + row*128 + (kb ^ ((row&7)<<4)));
    }
    #pragma unroll
    for (int mf=0;mf<4;mf++){
      #pragma unroll
      for (int nf=0;nf<4;nf++){
        acc[mf][nf] = __builtin_amdgcn_mfma_f32_16x16x32_bf16(af[mf], bfr[nf], acc[mf][nf], 0,0,0);
      }
    }
  }
}
// BM=64, BN=128: wave wv covers rows 0..63, cols wv*32..wv*32+31
__device__ __forceinline__ void mfma64(const char* AsB, const char* BsB,
    float4v acc[4][2], int lane, int wv){
  #pragma unroll
  for (int kk=0;kk<2;kk++){
    short8 af[4], bfr[2];
    const int kb = kk*64 + (lane>>4)*16;
    #pragma unroll
    for (int mf=0;mf<4;mf++){
      int row = mf*16 + (lane&15);
      af[mf] = *(const short8*)(AsB + row*128 + (kb ^ ((row&7)<<4)));
    }
    #pragma unroll
    for (int nf=0;nf<2;nf++){
      int row = wv*32 + nf*16 + (lane&15);
      bfr[nf] = *(const short8*)(BsB + row*128 + (kb ^ ((row&7)<<4)));
    }
    #pragma unroll
    for (int mf=0;mf<4;mf++){
      #pragma unroll
      for (int nf=0;nf<2;nf++){
        acc[mf][nf] = __builtin_amdgcn_mfma_f32_16x16x32_bf16(af[mf], bfr[nf], acc[mf][nf], 0,0,0);
      }
    }
  }
}

__device__ __forceinline__ void epi_store_bf4(ushort_t* C, int N, int m0, int n0,
    int lane, int wr, int wc, float4v acc[4][4]){
  #pragma unroll
  for (int mf=0;mf<4;mf++){
    int rbase = m0 + wr*64 + mf*16 + (lane>>4)*4;
    #pragma unroll
    for (int nf=0;nf<4;nf++){
      int col = n0 + wc*64 + nf*16 + (lane&15);
      #pragma unroll
      for (int r=0;r<4;r++){
        C[(size_t)(rbase+r)*N + col] = f2bf(acc[mf][nf][r]);
      }
    }
  }
}
__device__ __forceinline__ void epi_store64(ushort_t* C, int N, int m0, int n0,
    int lane, int wv, float4v acc[4][2]){
  #pragma unroll
  for (int mf=0;mf<4;mf++){
    int rbase = m0 + mf*16 + (lane>>4)*4;
    #pragma unroll
    for (int nf=0;nf<2;nf++){
      int col = n0 + wv*32 + nf*16 + (lane&15);
      #pragma unroll
      for (int r=0;r<4;r++){
        C[(size_t)(rbase+r)*N + col] = f2bf(acc[mf][nf][r]);
      }
    }
  }
}

// ---- setup kernels ----
__global__ void zero_kernel(float* loss, int* counts, float* zpage){
  int t = threadIdx.x;
  if (t==0) *loss = 0.0f;
  if (t<NLEV) counts[t]=0;
  zpage[t] = 0.0f;          // 1KB zero page
}

// W1t[512][512], W2t[640][256], W3hh_t[1024][256] (gate-interleaved rows),
// W3ih_t[1024][128] (gate-interleaved rows), embbf[640][128] (zero-padded)
__global__ void prep_kernel(const float* __restrict__ W_ph1, const float* __restrict__ W_ph2,
    const float* __restrict__ W_gate, const float* __restrict__ W_topo,
    const float* __restrict__ W_pred, const float* __restrict__ W_ih,
    const float* __restrict__ W_hh, const float* __restrict__ emb_table,
    ushort_t* __restrict__ W1t, ushort_t* __restrict__ W2t,
    ushort_t* __restrict__ W3hh, ushort_t* __restrict__ W3ih,
    ushort_t* __restrict__ embbf)
{
  int idx = blockIdx.x*256 + threadIdx.x;
  if (idx < 512*512){
    int o = idx >> 9, k = idx & 511;
    float v;
    if (o < 256) v = (k<256) ? W_ph1[k*256+o] : W_ph2[(k-256)*256+o];
    else         v = (k<256) ? 0.0f : W_gate[(k-256)*256+(o-256)];
    W1t[idx] = f2bf(v);
    return;
  }
  idx -= 512*512;
  if (idx < 640*256){
    int o = idx >> 8, k = idx & 255;
    float v = 0.0f;
    if (o < 3) v = W_topo[k*3+o];
    else if (o >= 8 && o < 608) v = W_pred[k*VOCAB + (o-8)];
    W2t[idx] = f2bf(v);
    return;
  }
  idx -= 640*256;
  if (idx < 1024*256){
    int r = idx >> 8, k = idx & 255;
    int orig = (r&3)*256 + (r>>2);       // row = 4*latent + gate (i,f,g,o)
    W3hh[idx] = f2bf(W_hh[orig*256+k]);
    return;
  }
  idx -= 1024*256;
  if (idx < 1024*128){
    int r = idx >> 7, k = idx & 127;
    int orig = (r&3)*256 + (r>>2);
    W3ih[idx] = f2bf(W_ih[orig*128+k]);
    return;
  }
  idx -= 1024*128;
  if (idx < 640*128){
    int r = idx >> 7, k = idx & 127;
    embbf[idx] = (r < VOCAB) ? f2bf(emb_table[r*EMBD+k]) : (ushort_t)0;
  }
}

// EG[640][1024] = embbf(640x128) @ W3ih(1024x128)^T  -- once per call
__global__ __launch_bounds__(256) void eg_gemm(
    const ushort_t* __restrict__ embbf, const ushort_t* __restrict__ W3ih,
    ushort_t* __restrict__ EG)
{
  const int m0 = blockIdx.x * 128;
  const int n0 = blockIdx.y * 128;
  __shared__ ushort_t As[128*64];
  __shared__ ushort_t Bs[128*64];
  char* AsB = (char*)As; char* BsB = (char*)Bs;
  const int t = threadIdx.x, lane = t&63, wv = t>>6, wr = wv>>1, wc = wv&1;
  const int srow = t>>3, skb = (t&7)*16;
  float4v acc[4][4];
  acc_zero4(acc);
  for (int k0 = 0; k0 < 128; k0 += 64){
    stageA128((const char*)embbf, 256, m0, k0, srow, skb, AsB, t);
    stageB128((const char*)W3ih, 256, n0, k0, srow, skb, BsB, t);
    __syncthreads();
    mfma_phase4(AsB, BsB, acc, lane, wr, wc);
    __syncthreads();
  }
  epi_store_bf4(EG, 1024, m0, n0, lane, wr, wc, acc);
}

__global__ __launch_bounds__(LATENT) void root_kernel(const float* __restrict__ z,
    const float* __restrict__ W, const float* __restrict__ b, float* __restrict__ root_h){
  __shared__ float zs[LATENT];
  int bi = blockIdx.x; int t = threadIdx.x;
  zs[t] = z[bi*LATENT+t];
  __syncthreads();
  float acc = b[t];
  for (int k=0;k<LATENT;k++) acc += zs[k]*W[t*LATENT+k];
  root_h[bi*LATENT+t] = acc;
}

__global__ __launch_bounds__(LATENT) void init_kernel(const int* __restrict__ node_level,
    const int* __restrict__ tree_id, const float* __restrict__ root_h,
    ushort_t* __restrict__ h_state, ushort_t* __restrict__ c_state){
  int t = threadIdx.x;
  for (int n = blockIdx.x; n < NNODES; n += gridDim.x){
    int lvl = node_level[n];
    ushort_t h = 0;
    if (lvl==0) h = f2bf(root_h[tree_id[n]*LATENT + t]);
    h_state[(size_t)n*LATENT+t]=h;
    c_state[(size_t)n*LATENT+t]=0;
  }
}

// LDS-histogram list builder: 1 global atomic per (block, level)
__global__ __launch_bounds__(256) void build_lists_kernel(const int* __restrict__ node_level,
    int* __restrict__ counts, int* __restrict__ lists){
  __shared__ int lcnt[NLEV];
  __shared__ int lbase[NLEV];
  int tt = threadIdx.x;
  int n = blockIdx.x*256 + tt;
  if (tt < NLEV) lcnt[tt] = 0;
  __syncthreads();
  int lvl = node_level[n];
  int pos = atomicAdd(&lcnt[lvl], 1);
  __syncthreads();
  if (tt < NLEV) lbase[tt] = atomicAdd(&counts[tt], lcnt[tt]);
  __syncthreads();
  if (lvl >= 1){
    int p = lbase[lvl] + pos;
    if (p < MAXM) lists[lvl*MAXM + p] = n;
  }
}

// ---- K1: gemm1 K-split into 6 uniform K=256 jobs, BM=64, BN=128.
//  y=0,1: hp @ Wph1  -> C1 cols (y&1)*128
//  y=2,3: hs @ Wph2  -> Cpb cols (y&1)*128
//  y=4,5: hs @ Wgate -> C1 cols 256+(y-4)*128 ----
__global__ __launch_bounds__(256) void k1_gemm(
    const int* __restrict__ counts, int lvl, const int* __restrict__ lists,
    const int* __restrict__ parent_idx, const int* __restrict__ sibling_idx,
    const int* __restrict__ has_prev, const ushort_t* __restrict__ h_state,
    const char* __restrict__ zpage, const ushort_t* __restrict__ W1t,
    ushort_t* __restrict__ C1, ushort_t* __restrict__ Cpb)
{
  const int count = min(counts[lvl], MAXM);
  const int m0 = blockIdx.x * 64;
  if (m0 >= count) return;
  const int y = blockIdx.y;
  const bool useHP = (y < 2);
  const int wk0 = useHP ? 0 : 256;                      // W1t K-offset
  const int orow0 = (y < 4) ? (y&1)*128 : 256 + (y-4)*128;  // W1t row / output col
  __shared__ ushort_t As[64*64];
  __shared__ ushort_t Bs[128*64];
  char* AsB = (char*)As; char* BsB = (char*)Bs;
  const int t = threadIdx.x, lane = t&63, wv = t>>6;
  const int srow = t>>3, skb = (t&7)*16;

  const char* ab[2]; int kbs[2];
  #pragma unroll
  for (int i=0;i<2;i++){
    int row = srow + 32*i;
    kbs[i] = skb ^ ((row&7)<<4);
    int m = m0 + row;
    if (m < count){
      int node = lists[lvl*MAXM + m];
      if (useHP){
        ab[i] = (const char*)(h_state + (size_t)parent_idx[node]*LATENT);
      } else {
        ab[i] = (has_prev[node] > 0) ? (const char*)(h_state + (size_t)sibling_idx[node]*LATENT)
                                     : zpage;
      }
    } else { ab[i] = zpage; }
  }

  float4v acc[4][2];
  acc_zero42(acc);

  for (int k0 = 0; k0 < 256; k0 += 64){
    #pragma unroll
    for (int i=0;i<2;i++){
      gload_lds(ab[i] + k0*2 + kbs[i], AsB + i*4096 + t*16);
    }
    stageB128((const char*)W1t, 1024, orow0, wk0 + k0, srow, skb, BsB, t);
    __syncthreads();
    mfma64(AsB, BsB, acc, lane, wv);
    __syncthreads();
  }
  if (y >= 2 && y < 4) epi_store64(Cpb, 256, m0, orow0, lane, wv, acc);
  else                 epi_store64(C1, 512, m0, orow0, lane, wv, acc);
}

// ---- mid: A2(lvl slab) = tanh(C1_pred + Cpb + b), PU = hp + sigm(C1_gate + b)*hs, Cpar ----
__global__ __launch_bounds__(256) void mid_kernel(
    const int* __restrict__ counts, int lvl, const int* __restrict__ lists,
    const int* __restrict__ parent_idx, const int* __restrict__ sibling_idx,
    const int* __restrict__ has_prev, const ushort_t* __restrict__ h_state,
    const ushort_t* __restrict__ c_state, const ushort_t* __restrict__ C1,
    const ushort_t* __restrict__ Cpb,
    const float* __restrict__ b_ph1, const float* __restrict__ b_ph2,
    const float* __restrict__ b_gate,
    ushort_t* __restrict__ A2, ushort_t* __restrict__ PU, ushort_t* __restrict__ Cpar)
{
  const int count = min(counts[lvl], MAXM);
  const int Mt = (count+127)&~127;
  const int t = threadIdx.x;
  const float bp = b_ph1[t] + b_ph2[t];
  const float bg = b_gate[t];
  for (int m = blockIdx.x; m < Mt; m += gridDim.x){
    if (m < count){
      int node = lists[lvl*MAXM + m];
      int pi = parent_idx[node];
      float hp = bf2f(h_state[(size_t)pi*LATENT + t]);
      float hs = (has_prev[node] > 0) ? bf2f(h_state[(size_t)sibling_idx[node]*LATENT + t]) : 0.0f;
      float pre  = bf2f(C1[(size_t)m*512 + t]) + bf2f(Cpb[(size_t)m*256 + t]) + bp;
      float gpre = bf2f(C1[(size_t)m*512 + 256 + t]) + bg;
      A2[(size_t)m*LATENT + t] = f2bf(tanhf(pre));
      PU[(size_t)m*LATENT + t] = f2bf(hp + sigm(gpre)*hs);
      Cpar[(size_t)m*LATENT + t] = c_state[(size_t)pi*LATENT + t];
    } else {
      A2[(size_t)m*LATENT + t] = 0;
      PU[(size_t)m*LATENT + t] = 0;
    }
  }
}

// ---- K2: gemm3 only (PU x W3hh -> C3), BM=64, BN=128 ----
__global__ __launch_bounds__(256) void k2_gemm3(
    const int* __restrict__ counts, int lvl,
    const ushort_t* __restrict__ PU, const ushort_t* __restrict__ W3hh,
    ushort_t* __restrict__ C3)
{
  const int count = min(counts[lvl], MAXM);
  const int id = blockIdx.x;
  __shared__ ushort_t As[64*64];
  __shared__ ushort_t Bs[128*64];
  char* AsB = (char*)As; char* BsB = (char*)Bs;
  const int t = threadIdx.x, lane = t&63, wv = t>>6;
  const int srow = t>>3, skb = (t&7)*16;
  const int m0 = (id>>3)*64; if (m0 >= count) return;
  const int n0 = (id&7)*128;
  float4v acc[4][2];
  acc_zero42(acc);
  for (int k0 = 0; k0 < 256; k0 += 64){
    stageA64((const char*)PU, 512, m0, k0, srow, skb, AsB, t);
    stageB128((const char*)W3hh, 512, n0, k0, srow, skb, BsB, t);
    __syncthreads();
    mfma64(AsB, BsB, acc, lane, wv);
    __syncthreads();
  }
  epi_store64(C3, 1024, m0, n0, lane, wv, acc);
}

// ---- K3: LSTM finish & scatter only ----
__global__ __launch_bounds__(256) void k3_lstm(
    const int* __restrict__ counts, int lvl, const int* __restrict__ lists,
    const ushort_t* __restrict__ C3,
    const ushort_t* __restrict__ Cpar, const ushort_t* __restrict__ EG,
    const float* __restrict__ b_ih, const float* __restrict__ b_hh,
    const int* __restrict__ features,
    ushort_t* __restrict__ h_state, ushort_t* __restrict__ c_state)
{
  const int count = min(counts[lvl], MAXM);
  const int t = threadIdx.x;
  const float bi = b_ih[t]       + b_hh[t];
  const float bf = b_ih[256+t]   + b_hh[256+t];
  const float bg = b_ih[512+t]   + b_hh[512+t];
  const float bo = b_ih[768+t]   + b_hh[768+t];
  for (int m = (int)blockIdx.x; m < count; m += gridDim.x){
    int node = lists[lvl*MAXM + m];
    int feat = features[node];
    u16x4 gv = *(const u16x4*)(C3 + (size_t)m*1024 + 4*t);     // PU@W_hh, interleaved
    u16x4 ev = *(const u16x4*)(EG + (size_t)feat*1024 + 4*t);  // emb@W_ih, interleaved
    float i_ = sigm(bf2f(gv[0]) + bf2f(ev[0]) + bi);
    float f_ = sigm(bf2f(gv[1]) + bf2f(ev[1]) + bf);
    float gg = tanhf(bf2f(gv[2]) + bf2f(ev[2]) + bg);
    float o_ = sigm(bf2f(gv[3]) + bf2f(ev[3]) + bo);
    float cn = f_*bf2f(Cpar[(size_t)m*LATENT+t]) + i_*gg;
    float hn = o_*tanhf(cn);
    h_state[(size_t)node*LATENT+t] = f2bf(hn);
    c_state[(size_t)node*LATENT+t] = f2bf(cn);
  }
}

// ---- batched loss GEMM: A-resident. BM=128, full N=640 per block via 5 n-chunks.
//      LDS: As 64KB (4 K-chunks) + Bs 16KB = 80KB -> 2 blocks/CU.
//      Online LSE across chunks in registers; final (M,S) written once. grid=(50,11) ----
__global__ __launch_bounds__(256) void loss_gemm(
    const int* __restrict__ counts, const int* __restrict__ lists,
    const int* __restrict__ features,
    const ushort_t* __restrict__ A2all, const ushort_t* __restrict__ W2t,
    const float* __restrict__ b_pred,
    float2v* __restrict__ LSE, float* __restrict__ Lf, float* __restrict__ TopoB)
{
  const int lvl = blockIdx.y + 1;
  const int count = min(counts[lvl], MAXM);
  const int m0 = blockIdx.x * 128;
  if (m0 >= count) return;
  const ushort_t* A2 = A2all + (size_t)lvl*MAXM*LATENT;
  float2v* LSEl = LSE + (size_t)lvl*MAXM;
  float* Lfl = Lf + (size_t)lvl*MAXM;
  float* Topol = TopoB + (size_t)lvl*MAXM*3;
  __shared__ ushort_t As[4*128*64];   // 64 KB: A tile [128][256] in 4 swizzled K-chunks
  __shared__ ushort_t Bs[128*64];     // 16 KB
  char* AsB = (char*)As; char* BsB = (char*)Bs;
  const int t = threadIdx.x, lane = t&63, wv = t>>6, wr = wv>>1, wc = wv&1;
  const int srow = t>>3, skb = (t&7)*16;

  // prologue: stage the whole A tile (stays resident for all 5 n-chunks)
  #pragma unroll
  for (int c=0;c<4;c++){
    stageA128((const char*)A2, 512, m0, c*64, srow, skb, AsB + c*16384, t);
  }
  // per-row feat targets for this thread's 16 (mf,r) slots
  int featr[16];
  #pragma unroll
  for (int j=0;j<16;j++){
    int row = wr*64 + (j>>2)*16 + (lane>>4)*4 + (j&3);
    int m = m0 + row;
    featr[j] = (m < count) ? (features[lists[lvl*MAXM + m]] + 8) : -9999;
  }
  float runM[16], runS[16];
  #pragma unroll
  for (int j=0;j<16;j++){ runM[j] = -1e30f; runS[j] = 0.0f; }

  for (int nchunk=0; nchunk<5; nchunk++){
    const int n0 = nchunk*128;
    float4v acc[4][4];
    acc_zero4(acc);
    #pragma unroll
    for (int c=0;c<4;c++){
      stageB128((const char*)W2t, 512, n0, c*64, srow, skb, BsB, t);
      __syncthreads();
      mfma_phase4(AsB + c*16384, BsB, acc, lane, wr, wc);
      __syncthreads();
    }
    // chunk epilogue: add bias, capture Lf/Topo, reduce 128-col partial, merge online
    int colv[4]; bool valid[4]; float bias[4];
    #pragma unroll
    for (int nf=0;nf<4;nf++){
      colv[nf] = n0 + wc*64 + nf*16 + (lane&15);
      valid[nf] = (colv[nf] >= 8 && colv[nf] < 608);
      bias[nf] = valid[nf] ? b_pred[colv[nf]-8] : 0.0f;
    }
    #pragma unroll
    for (int mf=0;mf<4;mf++){
      #pragma unroll
      for (int r=0;r<4;r++){
        int j = mf*4 + r;
        int row = wr*64 + mf*16 + (lane>>4)*4 + r;
        float v[4];
        #pragma unroll
        for (int nf=0;nf<4;nf++){
          float raw = acc[mf][nf][r];
          float val = raw + bias[nf];
          if (colv[nf] == featr[j]) Lfl[m0+row] = val;
          if (nchunk==0 && colv[nf] < 3) Topol[(size_t)(m0+row)*3 + colv[nf]] = raw;
          v[nf] = valid[nf] ? val : -1e30f;
        }
        float mx = fmaxf(fmaxf(v[0],v[1]), fmaxf(v[2],v[3]));
        #pragma unroll
        for (int off=8;off>=1;off>>=1) mx = fmaxf(mx, __shfl_xor(mx, off));
        float s = expf(v[0]-mx)+expf(v[1]-mx)+expf(v[2]-mx)+expf(v[3]-mx);
        #pragma unroll
        for (int off=8;off>=1;off>>=1) s += __shfl_xor(s, off);
        float nM = fmaxf(runM[j], mx);
        runS[j] = runS[j]*expf(runM[j]-nM) + s*expf(mx-nM);
        runM[j] = nM;
      }
    }
  }
  // final cross-wc combine (Bs is dead now)
  __syncthreads();
  float* scr = (float*)Bs;   // [128][2][2]
  if ((lane&15)==0){
    #pragma unroll
    for (int j=0;j<16;j++){
      int row = wr*64 + (j>>2)*16 + (lane>>4)*4 + (j&3);
      scr[row*4 + wc*2 + 0] = runM[j];
      scr[row*4 + wc*2 + 1] = runS[j];
    }
  }
  __syncthreads();
  if (t < 128){
    float M = fmaxf(scr[t*4+0], scr[t*4+2]);
    float S = scr[t*4+1]*expf(scr[t*4+0]-M)
            + scr[t*4+3]*expf(scr[t*4+2]-M);
    LSEl[m0+t] = (float2v){M, S};
  }
}

// ---- final loss merge: all levels. grid = (32, 11) ----
__global__ __launch_bounds__(256) void loss_merge(
    const int* __restrict__ counts, const int* __restrict__ lists,
    const float2v* __restrict__ LSE, const float* __restrict__ Lf,
    const float* __restrict__ TopoB,
    const float* __restrict__ b_topo,
    const int* __restrict__ is_parent, const int* __restrict__ has_sib,
    const int* __restrict__ is_res,
    float* __restrict__ loss)
{
  const int lvl = blockIdx.y + 1;
  const int count = min(counts[lvl], MAXM);
  const float2v* LSEl = LSE + (size_t)lvl*MAXM;
  const float* Lfl = Lf + (size_t)lvl*MAXM;
  const float* Topol = TopoB + (size_t)lvl*MAXM*3;
  __shared__ float lsum[4];
  const int wvi = threadIdx.x >> 6;
  if (threadIdx.x < 4) lsum[threadIdx.x] = 0.0f;
  __syncthreads();
  float acc = 0.0f;
  const float bt0 = b_topo[0], bt1 = b_topo[1], bt2 = b_topo[2];
  for (int m = blockIdx.x*256 + threadIdx.x; m < count; m += 8192){
    int node = lists[lvl*MAXM + m];
    float2v p = LSEl[m];
    float ce = logf(p[1]) + p[0] - Lfl[m];
    float bce = bcef(Topol[(size_t)m*3+0]+bt0, (float)is_parent[node])
              + bcef(Topol[(size_t)m*3+1]+bt1, (float)has_sib[node])
              + bcef(Topol[(size_t)m*3+2]+bt2, (float)is_res[node]);
    acc += ce + bce;
  }
  #pragma unroll
  for (int off=32;off>=1;off>>=1) acc += __shfl_xor(acc, off);
  if ((threadIdx.x&63)==0) atomicAdd(&lsum[wvi], acc);
  __syncthreads();
  if (threadIdx.x == 0){
    atomicAdd(loss, (lsum[0]+lsum[1]+lsum[2]+lsum[3]) * INV_N);
  }
}

extern "C" void kernel_launch(void* const* d_in, const int* in_sizes, int n_in,
                              void* d_out, int out_size, void* d_ws, size_t ws_size,
                              hipStream_t stream)
{
  const float* z         = (const float*)d_in[0];
  const float* emb_table = (const float*)d_in[1];
  const float* W_l2h     = (const float*)d_in[2];
  const float* b_l2h     = (const float*)d_in[3];
  const float* W_ih      = (const float*)d_in[4];
  const float* W_hh      = (const float*)d_in[5];
  const float* b_ih      = (const float*)d_in[6];
  const float* b_hh      = (const float*)d_in[7];
  const float* W_ph1     = (const float*)d_in[8];
  const float* b_ph1     = (const float*)d_in[9];
  const float* W_ph2     = (const float*)d_in[10];
  const float* b_ph2     = (const float*)d_in[11];
  const float* W_gate    = (const float*)d_in[12];
  const float* b_gate    = (const float*)d_in[13];
  const float* W_topo    = (const float*)d_in[14];
  const float* b_topo    = (const float*)d_in[15];
  const float* W_pred    = (const float*)d_in[16];
  const float* b_pred    = (const float*)d_in[17];
  const int* features    = (const int*)d_in[18];
  const int* node_level  = (const int*)d_in[19];
  const int* parent_idx  = (const int*)d_in[20];
  const int* sibling_idx = (const int*)d_in[21];
  const int* has_prev    = (const int*)d_in[22];
  const int* tree_id     = (const int*)d_in[23];
  const int* is_parent   = (const int*)d_in[24];
  const int* has_sib     = (const int*)d_in[25];
  const int* is_res      = (const int*)d_in[26];

  char* ws = (char*)d_ws;
  size_t off = 0;
  auto alloc = [&](size_t bytes)->char*{
    char* p = ws + off; off += (bytes + 255) & ~(size_t)255; return p;
  };
  ushort_t* h_state = (ushort_t*)alloc((size_t)NNODES*LATENT*2);   // 33.5 MB
  ushort_t* c_state = (ushort_t*)alloc((size_t)NNODES*LATENT*2);   // 33.5 MB
  ushort_t* A2all   = (ushort_t*)alloc((size_t)NLEV*MAXM*LATENT*2);// 39.3 MB
  ushort_t* PU      = (ushort_t*)alloc((size_t)MAXM*LATENT*2);
  ushort_t* C1      = (ushort_t*)alloc((size_t)MAXM*512*2);
  ushort_t* Cpb     = (ushort_t*)alloc((size_t)MAXM*256*2);
  ushort_t* C3      = (ushort_t*)alloc((size_t)MAXM*1024*2);
  ushort_t* Cpar    = (ushort_t*)alloc((size_t)MAXM*LATENT*2);
  float2v*  LSE     = (float2v*)alloc((size_t)NLEV*MAXM*8);
  float*    Lf      = (float*)alloc((size_t)NLEV*MAXM*4);
  float*    TopoB   = (float*)alloc((size_t)NLEV*MAXM*3*4);
  ushort_t* W1t     = (ushort_t*)alloc((size_t)512*512*2);
  ushort_t* W2t     = (ushort_t*)alloc((size_t)640*256*2);
  ushort_t* W3hh    = (ushort_t*)alloc((size_t)1024*256*2);
  ushort_t* W3ih    = (ushort_t*)alloc((size_t)1024*128*2);
  ushort_t* embbf   = (ushort_t*)alloc((size_t)640*128*2);
  ushort_t* EG      = (ushort_t*)alloc((size_t)640*1024*2);
  float*    root_h  = (float*)alloc((size_t)NTREES*LATENT*4);
  int*      lists   = (int*)alloc((size_t)NLEV*MAXM*4);
  int*      counts  = (int*)alloc(64);
  float*    zpage   = (float*)alloc(1024);
  float*    loss    = (float*)d_out;

  zero_kernel<<<1,256,0,stream>>>(loss, counts, zpage);
  prep_kernel<<<3520,256,0,stream>>>(W_ph1,W_ph2,W_gate,W_topo,W_pred,W_ih,W_hh,emb_table,
                                     W1t,W2t,W3hh,W3ih,embbf);
  eg_gemm<<<dim3(5,8),256,0,stream>>>(embbf, W3ih, EG);
  root_kernel<<<NTREES,LATENT,0,stream>>>(z, W_l2h, b_l2h, root_h);
  init_kernel<<<2048,LATENT,0,stream>>>(node_level, tree_id, root_h, h_state, c_state);
  build_lists_kernel<<<NNODES/256,256,0,stream>>>(node_level, counts, lists);

  for (int lvl=1; lvl<NLEV; lvl++){
    ushort_t* A2 = A2all + (size_t)lvl*MAXM*LATENT;
    k1_gemm<<<dim3(MAXM/64,6),256,0,stream>>>(counts, lvl, lists,
        parent_idx, sibling_idx, has_prev, h_state, (const char*)zpage, W1t, C1, Cpb);
    mid_kernel<<<2048,256,0,stream>>>(counts, lvl, lists, parent_idx, sibling_idx,
        has_prev, h_state, c_state, C1, Cpb, b_ph1, b_ph2, b_gate, A2, PU, Cpar);
    k2_gemm3<<<800,256,0,stream>>>(counts, lvl, PU, W3hh, C3);
    k3_lstm<<<2048,256,0,stream>>>(counts, lvl, lists, C3, Cpar, EG,
        b_ih, b_hh, features, h_state, c_state);
  }

  loss_gemm<<<dim3(50,NLEV-1),256,0,stream>>>(counts, lists, features,
      A2all, W2t, b_pred, LSE, Lf, TopoB);
  loss_merge<<<dim3(32,NLEV-1),256,0,stream>>>(counts, lists, LSE, Lf, TopoB,
      b_topo, is_parent, has_sib, is_res, loss);
}

// Round 20
// 497.098 us; speedup vs baseline: 1.1078x; 1.1078x over previous
//
#include <hip/hip_runtime.h>
#include <math.h>

#define LATENT 256
#define EMBD 128
#define VOCAB 600
#define NLEV 12
#define NNODES 65536
#define NTREES 32
#define MAXM 6400            // >= count(+13 sigma); multiple of 128
#define INV_N (1.0f/65536.0f)

typedef unsigned short ushort_t;
typedef __attribute__((ext_vector_type(8))) short short8;
typedef __attribute__((ext_vector_type(4))) float float4v;
typedef __attribute__((ext_vector_type(2))) float float2v;
typedef __attribute__((ext_vector_type(8))) unsigned short u16x8;
typedef __attribute__((ext_vector_type(4))) unsigned short u16x4;

#define GLOBAL_AS __attribute__((address_space(1)))
#define LDS_AS __attribute__((address_space(3)))

__device__ __forceinline__ float sigm(float x){ return 1.0f/(1.0f+expf(-x)); }
__device__ __forceinline__ float bcef(float x, float y){
  return fmaxf(x,0.0f) - x*y + log1pf(expf(-fabsf(x)));
}
__device__ __forceinline__ ushort_t f2bf(float f){
  union{float f; unsigned u;} v; v.f=f;
  unsigned r = v.u + 0x7fffu + ((v.u>>16)&1u);
  return (ushort_t)(r>>16);
}
__device__ __forceinline__ float bf2f(ushort_t u){
  union{unsigned u; float f;} v; v.u = ((unsigned)u)<<16; return v.f;
}

__device__ __forceinline__ void gload_lds(const void* src, void* dst){
  __builtin_amdgcn_global_load_lds((const GLOBAL_AS void*)src, (LDS_AS void*)dst, 16, 0, 0);
}

__device__ __forceinline__ void acc_zero4(float4v acc[4][4]){
  #pragma unroll
  for (int i=0;i<4;i++){
    #pragma unroll
    for (int j=0;j<4;j++){ acc[i][j] = (float4v){0.f,0.f,0.f,0.f}; }
  }
}
__device__ __forceinline__ void acc_zero42(float4v acc[4][2]){
  #pragma unroll
  for (int i=0;i<4;i++){
    #pragma unroll
    for (int j=0;j<2;j++){ acc[i][j] = (float4v){0.f,0.f,0.f,0.f}; }
  }
}

// ---- shared GEMM pieces (m97 structure, T2 swizzle) ----
__device__ __forceinline__ void stageB128(const char* Wb, int strideB, int n0, int k0,
    int srow, int skb, char* BsB, int t){
  #pragma unroll
  for (int i=0;i<4;i++){
    int row = srow + 32*i;
    int kbs = skb ^ ((row&7)<<4);
    const char* src = Wb + (size_t)(n0+row)*strideB + k0*2 + kbs;
    gload_lds(src, BsB + i*4096 + t*16);
  }
}
// direct (compact, padded) A staging, BM=128
__device__ __forceinline__ void stageA128(const char* Ab, int strideA, int m0, int k0,
    int srow, int skb, char* AsB, int t){
  #pragma unroll
  for (int i=0;i<4;i++){
    int row = srow + 32*i;
    int kbs = skb ^ ((row&7)<<4);
    const char* src = Ab + (size_t)(m0+row)*strideA + k0*2 + kbs;
    gload_lds(src, AsB + i*4096 + t*16);
  }
}
// direct (compact, padded) A staging, BM=64 (2 passes)
__device__ __forceinline__ void stageA64(const char* Ab, int strideA, int m0, int k0,
    int srow, int skb, char* AsB, int t){
  #pragma unroll
  for (int i=0;i<2;i++){
    int row = srow + 32*i;
    int kbs = skb ^ ((row&7)<<4);
    const char* src = Ab + (size_t)(m0+row)*strideA + k0*2 + kbs;
    gload_lds(src, AsB + i*4096 + t*16);
  }
}

__device__ __forceinline__ void mfma_phase4(const char* AsB, const char* BsB,
    float4v acc[4][4], int lane, int wr, int wc){
  #pragma unroll
  for (int kk=0;kk<2;kk++){
    short8 af[4], bfr[4];
    const int kb = kk*64 + (lane>>4)*16;
    #pragma unroll
    for (int mf=0;mf<4;mf++){
      int row = wr*64 + mf*16 + (lane&15);
      af[mf] = *(const short8*)(AsB + row*128 + (kb ^ ((row&7)<<4)));
    }
    #pragma unroll
    for (int nf=0;nf<4;nf++){
      int row = wc*64 + nf*16 + (lane&15);
      bfr[nf] = *(const short8*)(BsB + row*128 + (kb ^ ((row&7)<<4)));
    }
    #pragma unroll
    for (int mf=0;mf<4;mf++){
      #pragma unroll
      for (int nf=0;nf<4;nf++){
        acc[mf][nf] = __builtin_amdgcn_mfma_f32_16x16x32_bf16(af[mf], bfr[nf], acc[mf][nf], 0,0,0);
      }
    }
  }
}
// BM=64, BN=128: wave wv covers rows 0..63, cols wv*32..wv*32+31
__device__ __forceinline__ void mfma64(const char* AsB, const char* BsB,
    float4v acc[4][2], int lane, int wv){
  #pragma unroll
  for (int kk=0;kk<2;kk++){
    short8 af[4], bfr[2];
    const int kb = kk*64 + (lane>>4)*16;
    #pragma unroll
    for (int mf=0;mf<4;mf++){
      int row = mf*16 + (lane&15);
      af[mf] = *(const short8*)(AsB + row*128 + (kb ^ ((row&7)<<4)));
    }
    #pragma unroll
    for (int nf=0;nf<2;nf++){
      int row = wv*32 + nf*16 + (lane&15);
      bfr[nf] = *(const short8*)(BsB + row*128 + (kb ^ ((row&7)<<4)));
    }
    #pragma unroll
    for (int mf=0;mf<4;mf++){
      #pragma unroll
      for (int nf=0;nf<2;nf++){
        acc[mf][nf] = __builtin_amdgcn_mfma_f32_16x16x32_bf16(af[mf], bfr[nf], acc[mf][nf], 0,0,0);
      }
    }
  }
}

__device__ __forceinline__ void epi_store_bf4(ushort_t* C, int N, int m0, int n0,
    int lane, int wr, int wc, float4v acc[4][4]){
  #pragma unroll
  for (int mf=0;mf<4;mf++){
    int rbase = m0 + wr*64 + mf*16 + (lane>>4)*4;
    #pragma unroll
    for (int nf=0;nf<4;nf++){
      int col = n0 + wc*64 + nf*16 + (lane&15);
      #pragma unroll
      for (int r=0;r<4;r++){
        C[(size_t)(rbase+r)*N + col] = f2bf(acc[mf][nf][r]);
      }
    }
  }
}
__device__ __forceinline__ void epi_store64(ushort_t* C, int N, int m0, int n0,
    int lane, int wv, float4v acc[4][2]){
  #pragma unroll
  for (int mf=0;mf<4;mf++){
    int rbase = m0 + mf*16 + (lane>>4)*4;
    #pragma unroll
    for (int nf=0;nf<2;nf++){
      int col = n0 + wv*32 + nf*16 + (lane&15);
      #pragma unroll
      for (int r=0;r<4;r++){
        C[(size_t)(rbase+r)*N + col] = f2bf(acc[mf][nf][r]);
      }
    }
  }
}

// ---- setup kernels ----
__global__ void zero_kernel(float* loss, int* counts, float* zpage){
  int t = threadIdx.x;
  if (t==0) *loss = 0.0f;
  if (t<NLEV) counts[t]=0;
  zpage[t] = 0.0f;          // 1KB zero page
}

// W1t[512][512], W2t[640][256], W3hh_t[1024][256] (gate-interleaved rows),
// W3ih_t[1024][128] (gate-interleaved rows), embbf[640][128] (zero-padded)
__global__ void prep_kernel(const float* __restrict__ W_ph1, const float* __restrict__ W_ph2,
    const float* __restrict__ W_gate, const float* __restrict__ W_topo,
    const float* __restrict__ W_pred, const float* __restrict__ W_ih,
    const float* __restrict__ W_hh, const float* __restrict__ emb_table,
    ushort_t* __restrict__ W1t, ushort_t* __restrict__ W2t,
    ushort_t* __restrict__ W3hh, ushort_t* __restrict__ W3ih,
    ushort_t* __restrict__ embbf)
{
  int idx = blockIdx.x*256 + threadIdx.x;
  if (idx < 512*512){
    int o = idx >> 9, k = idx & 511;
    float v;
    if (o < 256) v = (k<256) ? W_ph1[k*256+o] : W_ph2[(k-256)*256+o];
    else         v = (k<256) ? 0.0f : W_gate[(k-256)*256+(o-256)];
    W1t[idx] = f2bf(v);
    return;
  }
  idx -= 512*512;
  if (idx < 640*256){
    int o = idx >> 8, k = idx & 255;
    float v = 0.0f;
    if (o < 3) v = W_topo[k*3+o];
    else if (o >= 8 && o < 608) v = W_pred[k*VOCAB + (o-8)];
    W2t[idx] = f2bf(v);
    return;
  }
  idx -= 640*256;
  if (idx < 1024*256){
    int r = idx >> 8, k = idx & 255;
    int orig = (r&3)*256 + (r>>2);       // row = 4*latent + gate (i,f,g,o)
    W3hh[idx] = f2bf(W_hh[orig*256+k]);
    return;
  }
  idx -= 1024*256;
  if (idx < 1024*128){
    int r = idx >> 7, k = idx & 127;
    int orig = (r&3)*256 + (r>>2);
    W3ih[idx] = f2bf(W_ih[orig*128+k]);
    return;
  }
  idx -= 1024*128;
  if (idx < 640*128){
    int r = idx >> 7, k = idx & 127;
    embbf[idx] = (r < VOCAB) ? f2bf(emb_table[r*EMBD+k]) : (ushort_t)0;
  }
}

// EG[640][1024] = embbf(640x128) @ W3ih(1024x128)^T  -- once per call
__global__ __launch_bounds__(256) void eg_gemm(
    const ushort_t* __restrict__ embbf, const ushort_t* __restrict__ W3ih,
    ushort_t* __restrict__ EG)
{
  const int m0 = blockIdx.x * 128;
  const int n0 = blockIdx.y * 128;
  __shared__ ushort_t As[128*64];
  __shared__ ushort_t Bs[128*64];
  char* AsB = (char*)As; char* BsB = (char*)Bs;
  const int t = threadIdx.x, lane = t&63, wv = t>>6, wr = wv>>1, wc = wv&1;
  const int srow = t>>3, skb = (t&7)*16;
  float4v acc[4][4];
  acc_zero4(acc);
  for (int k0 = 0; k0 < 128; k0 += 64){
    stageA128((const char*)embbf, 256, m0, k0, srow, skb, AsB, t);
    stageB128((const char*)W3ih, 256, n0, k0, srow, skb, BsB, t);
    __syncthreads();
    mfma_phase4(AsB, BsB, acc, lane, wr, wc);
    __syncthreads();
  }
  epi_store_bf4(EG, 1024, m0, n0, lane, wr, wc, acc);
}

__global__ __launch_bounds__(LATENT) void root_kernel(const float* __restrict__ z,
    const float* __restrict__ W, const float* __restrict__ b, float* __restrict__ root_h){
  __shared__ float zs[LATENT];
  int bi = blockIdx.x; int t = threadIdx.x;
  zs[t] = z[bi*LATENT+t];
  __syncthreads();
  float acc = b[t];
  for (int k=0;k<LATENT;k++) acc += zs[k]*W[t*LATENT+k];
  root_h[bi*LATENT+t] = acc;
}

__global__ __launch_bounds__(LATENT) void init_kernel(const int* __restrict__ node_level,
    const int* __restrict__ tree_id, const float* __restrict__ root_h,
    ushort_t* __restrict__ h_state, ushort_t* __restrict__ c_state){
  int t = threadIdx.x;
  for (int n = blockIdx.x; n < NNODES; n += gridDim.x){
    int lvl = node_level[n];
    ushort_t h = 0;
    if (lvl==0) h = f2bf(root_h[tree_id[n]*LATENT + t]);
    h_state[(size_t)n*LATENT+t]=h;
    c_state[(size_t)n*LATENT+t]=0;
  }
}

// LDS-histogram list builder: 1 global atomic per (block, level)
__global__ __launch_bounds__(256) void build_lists_kernel(const int* __restrict__ node_level,
    int* __restrict__ counts, int* __restrict__ lists){
  __shared__ int lcnt[NLEV];
  __shared__ int lbase[NLEV];
  int tt = threadIdx.x;
  int n = blockIdx.x*256 + tt;
  if (tt < NLEV) lcnt[tt] = 0;
  __syncthreads();
  int lvl = node_level[n];
  int pos = atomicAdd(&lcnt[lvl], 1);
  __syncthreads();
  if (tt < NLEV) lbase[tt] = atomicAdd(&counts[tt], lcnt[tt]);
  __syncthreads();
  if (lvl >= 1){
    int p = lbase[lvl] + pos;
    if (p < MAXM) lists[lvl*MAXM + p] = n;
  }
}

// ---- K1: gemm1 K-split into 6 uniform K=256 jobs, BM=64, BN=128.
//  y=0,1: hp @ Wph1  -> C1 cols (y&1)*128
//  y=2,3: hs @ Wph2  -> Cpb cols (y&1)*128
//  y=4,5: hs @ Wgate -> C1 cols 256+(y-4)*128 ----
__global__ __launch_bounds__(256) void k1_gemm(
    const int* __restrict__ counts, int lvl, const int* __restrict__ lists,
    const int* __restrict__ parent_idx, const int* __restrict__ sibling_idx,
    const int* __restrict__ has_prev, const ushort_t* __restrict__ h_state,
    const char* __restrict__ zpage, const ushort_t* __restrict__ W1t,
    ushort_t* __restrict__ C1, ushort_t* __restrict__ Cpb)
{
  const int count = min(counts[lvl], MAXM);
  const int m0 = blockIdx.x * 64;
  if (m0 >= count) return;
  const int y = blockIdx.y;
  const bool useHP = (y < 2);
  const int wk0 = useHP ? 0 : 256;                      // W1t K-offset
  const int orow0 = (y < 4) ? (y&1)*128 : 256 + (y-4)*128;  // W1t row / output col
  __shared__ ushort_t As[64*64];
  __shared__ ushort_t Bs[128*64];
  char* AsB = (char*)As; char* BsB = (char*)Bs;
  const int t = threadIdx.x, lane = t&63, wv = t>>6;
  const int srow = t>>3, skb = (t&7)*16;

  const char* ab[2]; int kbs[2];
  #pragma unroll
  for (int i=0;i<2;i++){
    int row = srow + 32*i;
    kbs[i] = skb ^ ((row&7)<<4);
    int m = m0 + row;
    if (m < count){
      int node = lists[lvl*MAXM + m];
      if (useHP){
        ab[i] = (const char*)(h_state + (size_t)parent_idx[node]*LATENT);
      } else {
        ab[i] = (has_prev[node] > 0) ? (const char*)(h_state + (size_t)sibling_idx[node]*LATENT)
                                     : zpage;
      }
    } else { ab[i] = zpage; }
  }

  float4v acc[4][2];
  acc_zero42(acc);

  for (int k0 = 0; k0 < 256; k0 += 64){
    #pragma unroll
    for (int i=0;i<2;i++){
      gload_lds(ab[i] + k0*2 + kbs[i], AsB + i*4096 + t*16);
    }
    stageB128((const char*)W1t, 1024, orow0, wk0 + k0, srow, skb, BsB, t);
    __syncthreads();
    mfma64(AsB, BsB, acc, lane, wv);
    __syncthreads();
  }
  if (y >= 2 && y < 4) epi_store64(Cpb, 256, m0, orow0, lane, wv, acc);
  else                 epi_store64(C1, 512, m0, orow0, lane, wv, acc);
}

// ---- mid: A2(lvl slab) = tanh(C1_pred + Cpb + b), PU = hp + sigm(C1_gate + b)*hs, Cpar ----
__global__ __launch_bounds__(256) void mid_kernel(
    const int* __restrict__ counts, int lvl, const int* __restrict__ lists,
    const int* __restrict__ parent_idx, const int* __restrict__ sibling_idx,
    const int* __restrict__ has_prev, const ushort_t* __restrict__ h_state,
    const ushort_t* __restrict__ c_state, const ushort_t* __restrict__ C1,
    const ushort_t* __restrict__ Cpb,
    const float* __restrict__ b_ph1, const float* __restrict__ b_ph2,
    const float* __restrict__ b_gate,
    ushort_t* __restrict__ A2, ushort_t* __restrict__ PU, ushort_t* __restrict__ Cpar)
{
  const int count = min(counts[lvl], MAXM);
  const int Mt = (count+127)&~127;
  const int t = threadIdx.x;
  const float bp = b_ph1[t] + b_ph2[t];
  const float bg = b_gate[t];
  for (int m = blockIdx.x; m < Mt; m += gridDim.x){
    if (m < count){
      int node = lists[lvl*MAXM + m];
      int pi = parent_idx[node];
      float hp = bf2f(h_state[(size_t)pi*LATENT + t]);
      float hs = (has_prev[node] > 0) ? bf2f(h_state[(size_t)sibling_idx[node]*LATENT + t]) : 0.0f;
      float pre  = bf2f(C1[(size_t)m*512 + t]) + bf2f(Cpb[(size_t)m*256 + t]) + bp;
      float gpre = bf2f(C1[(size_t)m*512 + 256 + t]) + bg;
      A2[(size_t)m*LATENT + t] = f2bf(tanhf(pre));
      PU[(size_t)m*LATENT + t] = f2bf(hp + sigm(gpre)*hs);
      Cpar[(size_t)m*LATENT + t] = c_state[(size_t)pi*LATENT + t];
    } else {
      A2[(size_t)m*LATENT + t] = 0;
      PU[(size_t)m*LATENT + t] = 0;
    }
  }
}

// ---- K2: gemm3 only (PU x W3hh -> C3), BM=64, BN=128 ----
__global__ __launch_bounds__(256) void k2_gemm3(
    const int* __restrict__ counts, int lvl,
    const ushort_t* __restrict__ PU, const ushort_t* __restrict__ W3hh,
    ushort_t* __restrict__ C3)
{
  const int count = min(counts[lvl], MAXM);
  const int id = blockIdx.x;
  __shared__ ushort_t As[64*64];
  __shared__ ushort_t Bs[128*64];
  char* AsB = (char*)As; char* BsB = (char*)Bs;
  const int t = threadIdx.x, lane = t&63, wv = t>>6;
  const int srow = t>>3, skb = (t&7)*16;
  const int m0 = (id>>3)*64; if (m0 >= count) return;
  const int n0 = (id&7)*128;
  float4v acc[4][2];
  acc_zero42(acc);
  for (int k0 = 0; k0 < 256; k0 += 64){
    stageA64((const char*)PU, 512, m0, k0, srow, skb, AsB, t);
    stageB128((const char*)W3hh, 512, n0, k0, srow, skb, BsB, t);
    __syncthreads();
    mfma64(AsB, BsB, acc, lane, wv);
    __syncthreads();
  }
  epi_store64(C3, 1024, m0, n0, lane, wv, acc);
}

// ---- K3: LSTM finish & scatter only ----
__global__ __launch_bounds__(256) void k3_lstm(
    const int* __restrict__ counts, int lvl, const int* __restrict__ lists,
    const ushort_t* __restrict__ C3,
    const ushort_t* __restrict__ Cpar, const ushort_t* __restrict__ EG,
    const float* __restrict__ b_ih, const float* __restrict__ b_hh,
    const int* __restrict__ features,
    ushort_t* __restrict__ h_state, ushort_t* __restrict__ c_state)
{
  const int count = min(counts[lvl], MAXM);
  const int t = threadIdx.x;
  const float bi = b_ih[t]       + b_hh[t];
  const float bf = b_ih[256+t]   + b_hh[256+t];
  const float bg = b_ih[512+t]   + b_hh[512+t];
  const float bo = b_ih[768+t]   + b_hh[768+t];
  for (int m = (int)blockIdx.x; m < count; m += gridDim.x){
    int node = lists[lvl*MAXM + m];
    int feat = features[node];
    u16x4 gv = *(const u16x4*)(C3 + (size_t)m*1024 + 4*t);     // PU@W_hh, interleaved
    u16x4 ev = *(const u16x4*)(EG + (size_t)feat*1024 + 4*t);  // emb@W_ih, interleaved
    float i_ = sigm(bf2f(gv[0]) + bf2f(ev[0]) + bi);
    float f_ = sigm(bf2f(gv[1]) + bf2f(ev[1]) + bf);
    float gg = tanhf(bf2f(gv[2]) + bf2f(ev[2]) + bg);
    float o_ = sigm(bf2f(gv[3]) + bf2f(ev[3]) + bo);
    float cn = f_*bf2f(Cpar[(size_t)m*LATENT+t]) + i_*gg;
    float hn = o_*tanhf(cn);
    h_state[(size_t)node*LATENT+t] = f2bf(hn);
    c_state[(size_t)node*LATENT+t] = f2bf(cn);
  }
}

// ---- batched loss GEMM: all 11 levels, BM=128, BN=128. grid = (250, 11).
//      LDS = 32 KB (As|Bs); lse/feat scratch aliased into As post-K-loop ----
__global__ __launch_bounds__(256) void loss_gemm(
    const int* __restrict__ counts, const int* __restrict__ lists,
    const int* __restrict__ features,
    const ushort_t* __restrict__ A2all, const ushort_t* __restrict__ W2t,
    const float* __restrict__ b_pred,
    float2v* __restrict__ LSEp, float* __restrict__ Lf, float* __restrict__ TopoB)
{
  const int lvl = blockIdx.y + 1;
  const int count = min(counts[lvl], MAXM);
  const int id = blockIdx.x;
  const ushort_t* A2 = A2all + (size_t)lvl*MAXM*LATENT;
  float2v* LSEl = LSEp + (size_t)lvl*MAXM*5;
  float* Lfl = Lf + (size_t)lvl*MAXM;
  float* Topol = TopoB + (size_t)lvl*MAXM*3;
  __shared__ ushort_t SMEM[2*128*64];     // As | Bs = 32 KB
  char* AsB = (char*)SMEM;
  char* BsB = (char*)(SMEM + 128*64);
  float* lse_lds = (float*)SMEM;          // [128][2][2] floats (2 KB) — aliases As, post-loop
  int* sh_feat = (int*)((char*)SMEM + 4096);  // 512 B — aliases As, post-loop
  const int t = threadIdx.x, lane = t&63, wv = t>>6, wr = wv>>1, wc = wv&1;
  const int srow = t>>3, skb = (t&7)*16;

  const int m0 = (id/5)*128; if (m0 >= count) return;
  const int nblk = id%5;
  const int n0 = nblk*128;
  float4v acc[4][4];
  acc_zero4(acc);
  for (int k0 = 0; k0 < 256; k0 += 64){
    stageA128((const char*)A2, 512, m0, k0, srow, skb, AsB, t);
    stageB128((const char*)W2t, 512, n0, k0, srow, skb, BsB, t);
    __syncthreads();
    mfma_phase4(AsB, BsB, acc, lane, wr, wc);
    __syncthreads();
  }
  // As is dead; reuse for epilogue scratch
  if (t < 128){
    int m = m0 + t;
    sh_feat[t] = (m < count) ? (features[lists[lvl*MAXM + m]] + 8) : -9999;
  }
  __syncthreads();
  // epilogue: per-row partial LSE over this block's 128 cols (wave half = 64 cols)
  int colv[4]; bool valid[4]; float bias[4];
  #pragma unroll
  for (int nf=0;nf<4;nf++){
    colv[nf] = n0 + wc*64 + nf*16 + (lane&15);
    valid[nf] = (colv[nf] >= 8 && colv[nf] < 608);
    bias[nf] = valid[nf] ? b_pred[colv[nf]-8] : 0.0f;
  }
  #pragma unroll
  for (int mf=0;mf<4;mf++){
    #pragma unroll
    for (int r=0;r<4;r++){
      int row = wr*64 + mf*16 + (lane>>4)*4 + r;
      float v[4];
      #pragma unroll
      for (int nf=0;nf<4;nf++){
        float raw = acc[mf][nf][r];
        float val = raw + bias[nf];
        if (colv[nf] == sh_feat[row]) Lfl[m0+row] = val;
        if (nblk==0 && colv[nf] < 3) Topol[(size_t)(m0+row)*3 + colv[nf]] = raw;
        v[nf] = valid[nf] ? val : -1e30f;
      }
      float mx = fmaxf(fmaxf(v[0],v[1]), fmaxf(v[2],v[3]));
      #pragma unroll
      for (int off=8;off>=1;off>>=1) mx = fmaxf(mx, __shfl_xor(mx, off));
      float s = expf(v[0]-mx)+expf(v[1]-mx)+expf(v[2]-mx)+expf(v[3]-mx);
      #pragma unroll
      for (int off=8;off>=1;off>>=1) s += __shfl_xor(s, off);
      if ((lane&15)==0){
        lse_lds[row*4 + wc*2 + 0] = mx;
        lse_lds[row*4 + wc*2 + 1] = s;
      }
    }
  }
  __syncthreads();
  if (t < 128){
    float M = fmaxf(lse_lds[t*4+0], lse_lds[t*4+2]);
    float S = lse_lds[t*4+1]*expf(lse_lds[t*4+0]-M)
            + lse_lds[t*4+3]*expf(lse_lds[t*4+2]-M);
    LSEl[(size_t)(m0+t)*5 + nblk] = (float2v){M, S};
  }
}

// ---- final loss merge: all levels. grid = (32, 11) ----
__global__ __launch_bounds__(256) void loss_merge(
    const int* __restrict__ counts, const int* __restrict__ lists,
    const float2v* __restrict__ LSEp, const float* __restrict__ Lf,
    const float* __restrict__ TopoB,
    const float* __restrict__ b_topo,
    const int* __restrict__ is_parent, const int* __restrict__ has_sib,
    const int* __restrict__ is_res,
    float* __restrict__ loss)
{
  const int lvl = blockIdx.y + 1;
  const int count = min(counts[lvl], MAXM);
  const float2v* LSEl = LSEp + (size_t)lvl*MAXM*5;
  const float* Lfl = Lf + (size_t)lvl*MAXM;
  const float* Topol = TopoB + (size_t)lvl*MAXM*3;
  __shared__ float lsum[4];
  const int wvi = threadIdx.x >> 6;
  if (threadIdx.x < 4) lsum[threadIdx.x] = 0.0f;
  __syncthreads();
  float acc = 0.0f;
  const float bt0 = b_topo[0], bt1 = b_topo[1], bt2 = b_topo[2];
  for (int m = blockIdx.x*256 + threadIdx.x; m < count; m += 8192){
    int node = lists[lvl*MAXM + m];
    float M = -1e30f;
    float2v p[5];
    #pragma unroll
    for (int b=0;b<5;b++){ p[b] = LSEl[(size_t)m*5 + b]; M = fmaxf(M, p[b][0]); }
    float S = 0.0f;
    #pragma unroll
    for (int b=0;b<5;b++) S += p[b][1] * expf(p[b][0] - M);
    float ce = logf(S) + M - Lfl[m];
    float bce = bcef(Topol[(size_t)m*3+0]+bt0, (float)is_parent[node])
              + bcef(Topol[(size_t)m*3+1]+bt1, (float)has_sib[node])
              + bcef(Topol[(size_t)m*3+2]+bt2, (float)is_res[node]);
    acc += ce + bce;
  }
  #pragma unroll
  for (int off=32;off>=1;off>>=1) acc += __shfl_xor(acc, off);
  if ((threadIdx.x&63)==0) atomicAdd(&lsum[wvi], acc);
  __syncthreads();
  if (threadIdx.x == 0){
    atomicAdd(loss, (lsum[0]+lsum[1]+lsum[2]+lsum[3]) * INV_N);
  }
}

extern "C" void kernel_launch(void* const* d_in, const int* in_sizes, int n_in,
                              void* d_out, int out_size, void* d_ws, size_t ws_size,
                              hipStream_t stream)
{
  const float* z         = (const float*)d_in[0];
  const float* emb_table = (const float*)d_in[1];
  const float* W_l2h     = (const float*)d_in[2];
  const float* b_l2h     = (const float*)d_in[3];
  const float* W_ih      = (const float*)d_in[4];
  const float* W_hh      = (const float*)d_in[5];
  const float* b_ih      = (const float*)d_in[6];
  const float* b_hh      = (const float*)d_in[7];
  const float* W_ph1     = (const float*)d_in[8];
  const float* b_ph1     = (const float*)d_in[9];
  const float* W_ph2     = (const float*)d_in[10];
  const float* b_ph2     = (const float*)d_in[11];
  const float* W_gate    = (const float*)d_in[12];
  const float* b_gate    = (const float*)d_in[13];
  const float* W_topo    = (const float*)d_in[14];
  const float* b_topo    = (const float*)d_in[15];
  const float* W_pred    = (const float*)d_in[16];
  const float* b_pred    = (const float*)d_in[17];
  const int* features    = (const int*)d_in[18];
  const int* node_level  = (const int*)d_in[19];
  const int* parent_idx  = (const int*)d_in[20];
  const int* sibling_idx = (const int*)d_in[21];
  const int* has_prev    = (const int*)d_in[22];
  const int* tree_id     = (const int*)d_in[23];
  const int* is_parent   = (const int*)d_in[24];
  const int* has_sib     = (const int*)d_in[25];
  const int* is_res      = (const int*)d_in[26];

  char* ws = (char*)d_ws;
  size_t off = 0;
  auto alloc = [&](size_t bytes)->char*{
    char* p = ws + off; off += (bytes + 255) & ~(size_t)255; return p;
  };
  ushort_t* h_state = (ushort_t*)alloc((size_t)NNODES*LATENT*2);   // 33.5 MB
  ushort_t* c_state = (ushort_t*)alloc((size_t)NNODES*LATENT*2);   // 33.5 MB
  ushort_t* A2all   = (ushort_t*)alloc((size_t)NLEV*MAXM*LATENT*2);// 39.3 MB
  ushort_t* PU      = (ushort_t*)alloc((size_t)MAXM*LATENT*2);
  ushort_t* C1      = (ushort_t*)alloc((size_t)MAXM*512*2);
  ushort_t* Cpb     = (ushort_t*)alloc((size_t)MAXM*256*2);
  ushort_t* C3      = (ushort_t*)alloc((size_t)MAXM*1024*2);
  ushort_t* Cpar    = (ushort_t*)alloc((size_t)MAXM*LATENT*2);
  float2v*  LSEp    = (float2v*)alloc((size_t)NLEV*MAXM*5*8);      // 3.1 MB
  float*    Lf      = (float*)alloc((size_t)NLEV*MAXM*4);
  float*    TopoB   = (float*)alloc((size_t)NLEV*MAXM*3*4);
  ushort_t* W1t     = (ushort_t*)alloc((size_t)512*512*2);
  ushort_t* W2t     = (ushort_t*)alloc((size_t)640*256*2);
  ushort_t* W3hh    = (ushort_t*)alloc((size_t)1024*256*2);
  ushort_t* W3ih    = (ushort_t*)alloc((size_t)1024*128*2);
  ushort_t* embbf   = (ushort_t*)alloc((size_t)640*128*2);
  ushort_t* EG      = (ushort_t*)alloc((size_t)640*1024*2);
  float*    root_h  = (float*)alloc((size_t)NTREES*LATENT*4);
  int*      lists   = (int*)alloc((size_t)NLEV*MAXM*4);
  int*      counts  = (int*)alloc(64);
  float*    zpage   = (float*)alloc(1024);
  float*    loss    = (float*)d_out;

  zero_kernel<<<1,256,0,stream>>>(loss, counts, zpage);
  prep_kernel<<<3520,256,0,stream>>>(W_ph1,W_ph2,W_gate,W_topo,W_pred,W_ih,W_hh,emb_table,
                                     W1t,W2t,W3hh,W3ih,embbf);
  eg_gemm<<<dim3(5,8),256,0,stream>>>(embbf, W3ih, EG);
  root_kernel<<<NTREES,LATENT,0,stream>>>(z, W_l2h, b_l2h, root_h);
  init_kernel<<<2048,LATENT,0,stream>>>(node_level, tree_id, root_h, h_state, c_state);
  build_lists_kernel<<<NNODES/256,256,0,stream>>>(node_level, counts, lists);

  for (int lvl=1; lvl<NLEV; lvl++){
    ushort_t* A2 = A2all + (size_t)lvl*MAXM*LATENT;
    k1_gemm<<<dim3(MAXM/64,6),256,0,stream>>>(counts, lvl, lists,
        parent_idx, sibling_idx, has_prev, h_state, (const char*)zpage, W1t, C1, Cpb);
    mid_kernel<<<4096,256,0,stream>>>(counts, lvl, lists, parent_idx, sibling_idx,
        has_prev, h_state, c_state, C1, Cpb, b_ph1, b_ph2, b_gate, A2, PU, Cpar);
    k2_gemm3<<<800,256,0,stream>>>(counts, lvl, PU, W3hh, C3);
    k3_lstm<<<4096,256,0,stream>>>(counts, lvl, lists, C3, Cpar, EG,
        b_ih, b_hh, features, h_state, c_state);
  }

  loss_gemm<<<dim3(250,NLEV-1),256,0,stream>>>(counts, lists, features,
      A2all, W2t, b_pred, LSEp, Lf, TopoB);
  loss_merge<<<dim3(32,NLEV-1),256,0,stream>>>(counts, lists, LSEp, Lf, TopoB,
      b_topo, is_parent, has_sib, is_res, loss);
}

// Round 21
// 485.139 us; speedup vs baseline: 1.1351x; 1.0247x over previous
//
#include <hip/hip_runtime.h>
#include <math.h>

#define LATENT 256
#define EMBD 128
#define VOCAB 600
#define NLEV 12
#define NNODES 65536
#define NTREES 32
#define MAXM 6400            // >= count(+13 sigma); multiple of 128
#define INV_N (1.0f/65536.0f)

typedef unsigned short ushort_t;
typedef __attribute__((ext_vector_type(8))) short short8;
typedef __attribute__((ext_vector_type(4))) float float4v;
typedef __attribute__((ext_vector_type(2))) float float2v;
typedef __attribute__((ext_vector_type(8))) unsigned short u16x8;
typedef __attribute__((ext_vector_type(4))) unsigned short u16x4;

#define GLOBAL_AS __attribute__((address_space(1)))
#define LDS_AS __attribute__((address_space(3)))

__device__ __forceinline__ float sigm(float x){ return 1.0f/(1.0f+expf(-x)); }
__device__ __forceinline__ float bcef(float x, float y){
  return fmaxf(x,0.0f) - x*y + log1pf(expf(-fabsf(x)));
}
__device__ __forceinline__ ushort_t f2bf(float f){
  union{float f; unsigned u;} v; v.f=f;
  unsigned r = v.u + 0x7fffu + ((v.u>>16)&1u);
  return (ushort_t)(r>>16);
}
__device__ __forceinline__ float bf2f(ushort_t u){
  union{unsigned u; float f;} v; v.u = ((unsigned)u)<<16; return v.f;
}

__device__ __forceinline__ void gload_lds(const void* src, void* dst){
  __builtin_amdgcn_global_load_lds((const GLOBAL_AS void*)src, (LDS_AS void*)dst, 16, 0, 0);
}

__device__ __forceinline__ void acc_zero4(float4v acc[4][4]){
  #pragma unroll
  for (int i=0;i<4;i++){
    #pragma unroll
    for (int j=0;j<4;j++){ acc[i][j] = (float4v){0.f,0.f,0.f,0.f}; }
  }
}
__device__ __forceinline__ void acc_zero42(float4v acc[4][2]){
  #pragma unroll
  for (int i=0;i<4;i++){
    #pragma unroll
    for (int j=0;j<2;j++){ acc[i][j] = (float4v){0.f,0.f,0.f,0.f}; }
  }
}

// ---- shared GEMM pieces (m97 structure, T2 swizzle) ----
__device__ __forceinline__ void stageB128(const char* Wb, int strideB, int n0, int k0,
    int srow, int skb, char* BsB, int t){
  #pragma unroll
  for (int i=0;i<4;i++){
    int row = srow + 32*i;
    int kbs = skb ^ ((row&7)<<4);
    const char* src = Wb + (size_t)(n0+row)*strideB + k0*2 + kbs;
    gload_lds(src, BsB + i*4096 + t*16);
  }
}
// direct (compact, padded) A staging, BM=128
__device__ __forceinline__ void stageA128(const char* Ab, int strideA, int m0, int k0,
    int srow, int skb, char* AsB, int t){
  #pragma unroll
  for (int i=0;i<4;i++){
    int row = srow + 32*i;
    int kbs = skb ^ ((row&7)<<4);
    const char* src = Ab + (size_t)(m0+row)*strideA + k0*2 + kbs;
    gload_lds(src, AsB + i*4096 + t*16);
  }
}
// direct (compact, padded) A staging, BM=64 (2 passes)
__device__ __forceinline__ void stageA64(const char* Ab, int strideA, int m0, int k0,
    int srow, int skb, char* AsB, int t){
  #pragma unroll
  for (int i=0;i<2;i++){
    int row = srow + 32*i;
    int kbs = skb ^ ((row&7)<<4);
    const char* src = Ab + (size_t)(m0+row)*strideA + k0*2 + kbs;
    gload_lds(src, AsB + i*4096 + t*16);
  }
}

__device__ __forceinline__ void mfma_phase4(const char* AsB, const char* BsB,
    float4v acc[4][4], int lane, int wr, int wc){
  #pragma unroll
  for (int kk=0;kk<2;kk++){
    short8 af[4], bfr[4];
    const int kb = kk*64 + (lane>>4)*16;
    #pragma unroll
    for (int mf=0;mf<4;mf++){
      int row = wr*64 + mf*16 + (lane&15);
      af[mf] = *(const short8*)(AsB + row*128 + (kb ^ ((row&7)<<4)));
    }
    #pragma unroll
    for (int nf=0;nf<4;nf++){
      int row = wc*64 + nf*16 + (lane&15);
      bfr[nf] = *(const short8*)(BsB + row*128 + (kb ^ ((row&7)<<4)));
    }
    #pragma unroll
    for (int mf=0;mf<4;mf++){
      #pragma unroll
      for (int nf=0;nf<4;nf++){
        acc[mf][nf] = __builtin_amdgcn_mfma_f32_16x16x32_bf16(af[mf], bfr[nf], acc[mf][nf], 0,0,0);
      }
    }
  }
}
// BM=64, BN=128: wave wv covers rows 0..63, cols wv*32..wv*32+31
__device__ __forceinline__ void mfma64(const char* AsB, const char* BsB,
    float4v acc[4][2], int lane, int wv){
  #pragma unroll
  for (int kk=0;kk<2;kk++){
    short8 af[4], bfr[2];
    const int kb = kk*64 + (lane>>4)*16;
    #pragma unroll
    for (int mf=0;mf<4;mf++){
      int row = mf*16 + (lane&15);
      af[mf] = *(const short8*)(AsB + row*128 + (kb ^ ((row&7)<<4)));
    }
    #pragma unroll
    for (int nf=0;nf<2;nf++){
      int row = wv*32 + nf*16 + (lane&15);
      bfr[nf] = *(const short8*)(BsB + row*128 + (kb ^ ((row&7)<<4)));
    }
    #pragma unroll
    for (int mf=0;mf<4;mf++){
      #pragma unroll
      for (int nf=0;nf<2;nf++){
        acc[mf][nf] = __builtin_amdgcn_mfma_f32_16x16x32_bf16(af[mf], bfr[nf], acc[mf][nf], 0,0,0);
      }
    }
  }
}

__device__ __forceinline__ void epi_store_bf4(ushort_t* C, int N, int m0, int n0,
    int lane, int wr, int wc, float4v acc[4][4]){
  #pragma unroll
  for (int mf=0;mf<4;mf++){
    int rbase = m0 + wr*64 + mf*16 + (lane>>4)*4;
    #pragma unroll
    for (int nf=0;nf<4;nf++){
      int col = n0 + wc*64 + nf*16 + (lane&15);
      #pragma unroll
      for (int r=0;r<4;r++){
        C[(size_t)(rbase+r)*N + col] = f2bf(acc[mf][nf][r]);
      }
    }
  }
}
__device__ __forceinline__ void epi_store64(ushort_t* C, int N, int m0, int n0,
    int lane, int wv, float4v acc[4][2]){
  #pragma unroll
  for (int mf=0;mf<4;mf++){
    int rbase = m0 + mf*16 + (lane>>4)*4;
    #pragma unroll
    for (int nf=0;nf<2;nf++){
      int col = n0 + wv*32 + nf*16 + (lane&15);
      #pragma unroll
      for (int r=0;r<4;r++){
        C[(size_t)(rbase+r)*N + col] = f2bf(acc[mf][nf][r]);
      }
    }
  }
}

// ---- setup kernels ----
__global__ void zero_kernel(float* loss, int* counts, float* zpage){
  int t = threadIdx.x;
  if (t==0) *loss = 0.0f;
  if (t<NLEV) counts[t]=0;
  zpage[t] = 0.0f;          // 1KB zero page
}

// W1t[512][512], W2t[640][256], W3hh_t[1024][256] (gate-interleaved rows),
// W3ih_t[1024][128] (gate-interleaved rows), embbf[640][128] (zero-padded)
__global__ void prep_kernel(const float* __restrict__ W_ph1, const float* __restrict__ W_ph2,
    const float* __restrict__ W_gate, const float* __restrict__ W_topo,
    const float* __restrict__ W_pred, const float* __restrict__ W_ih,
    const float* __restrict__ W_hh, const float* __restrict__ emb_table,
    ushort_t* __restrict__ W1t, ushort_t* __restrict__ W2t,
    ushort_t* __restrict__ W3hh, ushort_t* __restrict__ W3ih,
    ushort_t* __restrict__ embbf)
{
  int idx = blockIdx.x*256 + threadIdx.x;
  if (idx < 512*512){
    int o = idx >> 9, k = idx & 511;
    float v;
    if (o < 256) v = (k<256) ? W_ph1[k*256+o] : W_ph2[(k-256)*256+o];
    else         v = (k<256) ? 0.0f : W_gate[(k-256)*256+(o-256)];
    W1t[idx] = f2bf(v);
    return;
  }
  idx -= 512*512;
  if (idx < 640*256){
    int o = idx >> 8, k = idx & 255;
    float v = 0.0f;
    if (o < 3) v = W_topo[k*3+o];
    else if (o >= 8 && o < 608) v = W_pred[k*VOCAB + (o-8)];
    W2t[idx] = f2bf(v);
    return;
  }
  idx -= 640*256;
  if (idx < 1024*256){
    int r = idx >> 8, k = idx & 255;
    int orig = (r&3)*256 + (r>>2);       // row = 4*latent + gate (i,f,g,o)
    W3hh[idx] = f2bf(W_hh[orig*256+k]);
    return;
  }
  idx -= 1024*256;
  if (idx < 1024*128){
    int r = idx >> 7, k = idx & 127;
    int orig = (r&3)*256 + (r>>2);
    W3ih[idx] = f2bf(W_ih[orig*128+k]);
    return;
  }
  idx -= 1024*128;
  if (idx < 640*128){
    int r = idx >> 7, k = idx & 127;
    embbf[idx] = (r < VOCAB) ? f2bf(emb_table[r*EMBD+k]) : (ushort_t)0;
  }
}

// EG[640][1024] = embbf(640x128) @ W3ih(1024x128)^T  -- once per call
__global__ __launch_bounds__(256) void eg_gemm(
    const ushort_t* __restrict__ embbf, const ushort_t* __restrict__ W3ih,
    ushort_t* __restrict__ EG)
{
  const int m0 = blockIdx.x * 128;
  const int n0 = blockIdx.y * 128;
  __shared__ ushort_t As[128*64];
  __shared__ ushort_t Bs[128*64];
  char* AsB = (char*)As; char* BsB = (char*)Bs;
  const int t = threadIdx.x, lane = t&63, wv = t>>6, wr = wv>>1, wc = wv&1;
  const int srow = t>>3, skb = (t&7)*16;
  float4v acc[4][4];
  acc_zero4(acc);
  for (int k0 = 0; k0 < 128; k0 += 64){
    stageA128((const char*)embbf, 256, m0, k0, srow, skb, AsB, t);
    stageB128((const char*)W3ih, 256, n0, k0, srow, skb, BsB, t);
    __syncthreads();
    mfma_phase4(AsB, BsB, acc, lane, wr, wc);
    __syncthreads();
  }
  epi_store_bf4(EG, 1024, m0, n0, lane, wr, wc, acc);
}

__global__ __launch_bounds__(LATENT) void root_kernel(const float* __restrict__ z,
    const float* __restrict__ W, const float* __restrict__ b, float* __restrict__ root_h){
  __shared__ float zs[LATENT];
  int bi = blockIdx.x; int t = threadIdx.x;
  zs[t] = z[bi*LATENT+t];
  __syncthreads();
  float acc = b[t];
  for (int k=0;k<LATENT;k++) acc += zs[k]*W[t*LATENT+k];
  root_h[bi*LATENT+t] = acc;
}

__global__ __launch_bounds__(LATENT) void init_kernel(const int* __restrict__ node_level,
    const int* __restrict__ tree_id, const float* __restrict__ root_h,
    ushort_t* __restrict__ h_state, ushort_t* __restrict__ c_state){
  int t = threadIdx.x;
  for (int n = blockIdx.x; n < NNODES; n += gridDim.x){
    int lvl = node_level[n];
    ushort_t h = 0;
    if (lvl==0) h = f2bf(root_h[tree_id[n]*LATENT + t]);
    h_state[(size_t)n*LATENT+t]=h;
    c_state[(size_t)n*LATENT+t]=0;
  }
}

// LDS-histogram list builder: 1 global atomic per (block, level)
__global__ __launch_bounds__(256) void build_lists_kernel(const int* __restrict__ node_level,
    int* __restrict__ counts, int* __restrict__ lists){
  __shared__ int lcnt[NLEV];
  __shared__ int lbase[NLEV];
  int tt = threadIdx.x;
  int n = blockIdx.x*256 + tt;
  if (tt < NLEV) lcnt[tt] = 0;
  __syncthreads();
  int lvl = node_level[n];
  int pos = atomicAdd(&lcnt[lvl], 1);
  __syncthreads();
  if (tt < NLEV) lbase[tt] = atomicAdd(&counts[tt], lcnt[tt]);
  __syncthreads();
  if (lvl >= 1){
    int p = lbase[lvl] + pos;
    if (p < MAXM) lists[lvl*MAXM + p] = n;
  }
}

// ---- K1: gemm1 K-split into 6 uniform K=256 jobs, BM=64, BN=128.
//  y=0,1: hp @ Wph1  -> C1 cols (y&1)*128
//  y=2,3: hs @ Wph2  -> Cpb cols (y&1)*128
//  y=4,5: hs @ Wgate -> C1 cols 256+(y-4)*128 ----
__global__ __launch_bounds__(256) void k1_gemm(
    const int* __restrict__ counts, int lvl, const int* __restrict__ lists,
    const int* __restrict__ parent_idx, const int* __restrict__ sibling_idx,
    const int* __restrict__ has_prev, const ushort_t* __restrict__ h_state,
    const char* __restrict__ zpage, const ushort_t* __restrict__ W1t,
    ushort_t* __restrict__ C1, ushort_t* __restrict__ Cpb)
{
  const int count = min(counts[lvl], MAXM);
  const int m0 = blockIdx.x * 64;
  if (m0 >= count) return;
  const int y = blockIdx.y;
  const bool useHP = (y < 2);
  const int wk0 = useHP ? 0 : 256;                      // W1t K-offset
  const int orow0 = (y < 4) ? (y&1)*128 : 256 + (y-4)*128;  // W1t row / output col
  __shared__ ushort_t As[64*64];
  __shared__ ushort_t Bs[128*64];
  char* AsB = (char*)As; char* BsB = (char*)Bs;
  const int t = threadIdx.x, lane = t&63, wv = t>>6;
  const int srow = t>>3, skb = (t&7)*16;

  const char* ab[2]; int kbs[2];
  #pragma unroll
  for (int i=0;i<2;i++){
    int row = srow + 32*i;
    kbs[i] = skb ^ ((row&7)<<4);
    int m = m0 + row;
    if (m < count){
      int node = lists[lvl*MAXM + m];
      if (useHP){
        ab[i] = (const char*)(h_state + (size_t)parent_idx[node]*LATENT);
      } else {
        ab[i] = (has_prev[node] > 0) ? (const char*)(h_state + (size_t)sibling_idx[node]*LATENT)
                                     : zpage;
      }
    } else { ab[i] = zpage; }
  }

  float4v acc[4][2];
  acc_zero42(acc);

  for (int k0 = 0; k0 < 256; k0 += 64){
    #pragma unroll
    for (int i=0;i<2;i++){
      gload_lds(ab[i] + k0*2 + kbs[i], AsB + i*4096 + t*16);
    }
    stageB128((const char*)W1t, 1024, orow0, wk0 + k0, srow, skb, BsB, t);
    __syncthreads();
    mfma64(AsB, BsB, acc, lane, wv);
    __syncthreads();
  }
  if (y >= 2 && y < 4) epi_store64(Cpb, 256, m0, orow0, lane, wv, acc);
  else                 epi_store64(C1, 512, m0, orow0, lane, wv, acc);
}

// ---- mid: A2(lvl slab) = tanh(C1_pred + Cpb + b), PU = hp + sigm(C1_gate + b)*hs, Cpar ----
__global__ __launch_bounds__(256) void mid_kernel(
    const int* __restrict__ counts, int lvl, const int* __restrict__ lists,
    const int* __restrict__ parent_idx, const int* __restrict__ sibling_idx,
    const int* __restrict__ has_prev, const ushort_t* __restrict__ h_state,
    const ushort_t* __restrict__ c_state, const ushort_t* __restrict__ C1,
    const ushort_t* __restrict__ Cpb,
    const float* __restrict__ b_ph1, const float* __restrict__ b_ph2,
    const float* __restrict__ b_gate,
    ushort_t* __restrict__ A2, ushort_t* __restrict__ PU, ushort_t* __restrict__ Cpar)
{
  const int count = min(counts[lvl], MAXM);
  const int Mt = (count+127)&~127;
  const int t = threadIdx.x;
  const float bp = b_ph1[t] + b_ph2[t];
  const float bg = b_gate[t];
  for (int m = blockIdx.x; m < Mt; m += gridDim.x){
    if (m < count){
      int node = lists[lvl*MAXM + m];
      int pi = parent_idx[node];
      float hp = bf2f(h_state[(size_t)pi*LATENT + t]);
      float hs = (has_prev[node] > 0) ? bf2f(h_state[(size_t)sibling_idx[node]*LATENT + t]) : 0.0f;
      float pre  = bf2f(C1[(size_t)m*512 + t]) + bf2f(Cpb[(size_t)m*256 + t]) + bp;
      float gpre = bf2f(C1[(size_t)m*512 + 256 + t]) + bg;
      A2[(size_t)m*LATENT + t] = f2bf(tanhf(pre));
      PU[(size_t)m*LATENT + t] = f2bf(hp + sigm(gpre)*hs);
      Cpar[(size_t)m*LATENT + t] = c_state[(size_t)pi*LATENT + t];
    } else {
      A2[(size_t)m*LATENT + t] = 0;
      PU[(size_t)m*LATENT + t] = 0;
    }
  }
}

// ---- K2: gemm3 only (PU x W3hh -> C3), BM=64, BN=128 ----
__global__ __launch_bounds__(256) void k2_gemm3(
    const int* __restrict__ counts, int lvl,
    const ushort_t* __restrict__ PU, const ushort_t* __restrict__ W3hh,
    ushort_t* __restrict__ C3)
{
  const int count = min(counts[lvl], MAXM);
  const int id = blockIdx.x;
  __shared__ ushort_t As[64*64];
  __shared__ ushort_t Bs[128*64];
  char* AsB = (char*)As; char* BsB = (char*)Bs;
  const int t = threadIdx.x, lane = t&63, wv = t>>6;
  const int srow = t>>3, skb = (t&7)*16;
  const int m0 = (id>>3)*64; if (m0 >= count) return;
  const int n0 = (id&7)*128;
  float4v acc[4][2];
  acc_zero42(acc);
  for (int k0 = 0; k0 < 256; k0 += 64){
    stageA64((const char*)PU, 512, m0, k0, srow, skb, AsB, t);
    stageB128((const char*)W3hh, 512, n0, k0, srow, skb, BsB, t);
    __syncthreads();
    mfma64(AsB, BsB, acc, lane, wv);
    __syncthreads();
  }
  epi_store64(C3, 1024, m0, n0, lane, wv, acc);
}

// ---- K3: LSTM finish & scatter only ----
__global__ __launch_bounds__(256) void k3_lstm(
    const int* __restrict__ counts, int lvl, const int* __restrict__ lists,
    const ushort_t* __restrict__ C3,
    const ushort_t* __restrict__ Cpar, const ushort_t* __restrict__ EG,
    const float* __restrict__ b_ih, const float* __restrict__ b_hh,
    const int* __restrict__ features,
    ushort_t* __restrict__ h_state, ushort_t* __restrict__ c_state)
{
  const int count = min(counts[lvl], MAXM);
  const int t = threadIdx.x;
  const float bi = b_ih[t]       + b_hh[t];
  const float bf = b_ih[256+t]   + b_hh[256+t];
  const float bg = b_ih[512+t]   + b_hh[512+t];
  const float bo = b_ih[768+t]   + b_hh[768+t];
  for (int m = (int)blockIdx.x; m < count; m += gridDim.x){
    int node = lists[lvl*MAXM + m];
    int feat = features[node];
    u16x4 gv = *(const u16x4*)(C3 + (size_t)m*1024 + 4*t);     // PU@W_hh, interleaved
    u16x4 ev = *(const u16x4*)(EG + (size_t)feat*1024 + 4*t);  // emb@W_ih, interleaved
    float i_ = sigm(bf2f(gv[0]) + bf2f(ev[0]) + bi);
    float f_ = sigm(bf2f(gv[1]) + bf2f(ev[1]) + bf);
    float gg = tanhf(bf2f(gv[2]) + bf2f(ev[2]) + bg);
    float o_ = sigm(bf2f(gv[3]) + bf2f(ev[3]) + bo);
    float cn = f_*bf2f(Cpar[(size_t)m*LATENT+t]) + i_*gg;
    float hn = o_*tanhf(cn);
    h_state[(size_t)node*LATENT+t] = f2bf(hn);
    c_state[(size_t)node*LATENT+t] = f2bf(cn);
  }
}

// ---- batched loss GEMM: all 11 levels, BM=128, BN=128. grid = (250, 11).
//      LDS = 32 KB (As|Bs); lse/feat scratch aliased into As post-K-loop ----
__global__ __launch_bounds__(256) void loss_gemm(
    const int* __restrict__ counts, const int* __restrict__ lists,
    const int* __restrict__ features,
    const ushort_t* __restrict__ A2all, const ushort_t* __restrict__ W2t,
    const float* __restrict__ b_pred,
    float2v* __restrict__ LSEp, float* __restrict__ Lf, float* __restrict__ TopoB)
{
  const int lvl = blockIdx.y + 1;
  const int count = min(counts[lvl], MAXM);
  const int id = blockIdx.x;
  const ushort_t* A2 = A2all + (size_t)lvl*MAXM*LATENT;
  float2v* LSEl = LSEp + (size_t)lvl*MAXM*5;
  float* Lfl = Lf + (size_t)lvl*MAXM;
  float* Topol = TopoB + (size_t)lvl*MAXM*3;
  __shared__ ushort_t SMEM[2*128*64];     // As | Bs = 32 KB
  char* AsB = (char*)SMEM;
  char* BsB = (char*)(SMEM + 128*64);
  float* lse_lds = (float*)SMEM;          // [128][2][2] floats (2 KB) — aliases As, post-loop
  int* sh_feat = (int*)((char*)SMEM + 4096);  // 512 B — aliases As, post-loop
  const int t = threadIdx.x, lane = t&63, wv = t>>6, wr = wv>>1, wc = wv&1;
  const int srow = t>>3, skb = (t&7)*16;

  const int m0 = (id/5)*128; if (m0 >= count) return;
  const int nblk = id%5;
  const int n0 = nblk*128;
  float4v acc[4][4];
  acc_zero4(acc);
  for (int k0 = 0; k0 < 256; k0 += 64){
    stageA128((const char*)A2, 512, m0, k0, srow, skb, AsB, t);
    stageB128((const char*)W2t, 512, n0, k0, srow, skb, BsB, t);
    __syncthreads();
    mfma_phase4(AsB, BsB, acc, lane, wr, wc);
    __syncthreads();
  }
  // As is dead; reuse for epilogue scratch
  if (t < 128){
    int m = m0 + t;
    sh_feat[t] = (m < count) ? (features[lists[lvl*MAXM + m]] + 8) : -9999;
  }
  __syncthreads();
  // epilogue: per-row partial LSE over this block's 128 cols (wave half = 64 cols)
  int colv[4]; bool valid[4]; float bias[4];
  #pragma unroll
  for (int nf=0;nf<4;nf++){
    colv[nf] = n0 + wc*64 + nf*16 + (lane&15);
    valid[nf] = (colv[nf] >= 8 && colv[nf] < 608);
    bias[nf] = valid[nf] ? b_pred[colv[nf]-8] : 0.0f;
  }
  #pragma unroll
  for (int mf=0;mf<4;mf++){
    #pragma unroll
    for (int r=0;r<4;r++){
      int row = wr*64 + mf*16 + (lane>>4)*4 + r;
      float v[4];
      #pragma unroll
      for (int nf=0;nf<4;nf++){
        float raw = acc[mf][nf][r];
        float val = raw + bias[nf];
        if (colv[nf] == sh_feat[row]) Lfl[m0+row] = val;
        if (nblk==0 && colv[nf] < 3) Topol[(size_t)(m0+row)*3 + colv[nf]] = raw;
        v[nf] = valid[nf] ? val : -1e30f;
      }
      float mx = fmaxf(fmaxf(v[0],v[1]), fmaxf(v[2],v[3]));
      #pragma unroll
      for (int off=8;off>=1;off>>=1) mx = fmaxf(mx, __shfl_xor(mx, off));
      float s = expf(v[0]-mx)+expf(v[1]-mx)+expf(v[2]-mx)+expf(v[3]-mx);
      #pragma unroll
      for (int off=8;off>=1;off>>=1) s += __shfl_xor(s, off);
      if ((lane&15)==0){
        lse_lds[row*4 + wc*2 + 0] = mx;
        lse_lds[row*4 + wc*2 + 1] = s;
      }
    }
  }
  __syncthreads();
  if (t < 128){
    float M = fmaxf(lse_lds[t*4+0], lse_lds[t*4+2]);
    float S = lse_lds[t*4+1]*expf(lse_lds[t*4+0]-M)
            + lse_lds[t*4+3]*expf(lse_lds[t*4+2]-M);
    LSEl[(size_t)(m0+t)*5 + nblk] = (float2v){M, S};
  }
}

// ---- final loss merge: all levels. grid = (32, 11) ----
__global__ __launch_bounds__(256) void loss_merge(
    const int* __restrict__ counts, const int* __restrict__ lists,
    const float2v* __restrict__ LSEp, const float* __restrict__ Lf,
    const float* __restrict__ TopoB,
    const float* __restrict__ b_topo,
    const int* __restrict__ is_parent, const int* __restrict__ has_sib,
    const int* __restrict__ is_res,
    float* __restrict__ loss)
{
  const int lvl = blockIdx.y + 1;
  const int count = min(counts[lvl], MAXM);
  const float2v* LSEl = LSEp + (size_t)lvl*MAXM*5;
  const float* Lfl = Lf + (size_t)lvl*MAXM;
  const float* Topol = TopoB + (size_t)lvl*MAXM*3;
  __shared__ float lsum[4];
  const int wvi = threadIdx.x >> 6;
  if (threadIdx.x < 4) lsum[threadIdx.x] = 0.0f;
  __syncthreads();
  float acc = 0.0f;
  const float bt0 = b_topo[0], bt1 = b_topo[1], bt2 = b_topo[2];
  for (int m = blockIdx.x*256 + threadIdx.x; m < count; m += 8192){
    int node = lists[lvl*MAXM + m];
    float M = -1e30f;
    float2v p[5];
    #pragma unroll
    for (int b=0;b<5;b++){ p[b] = LSEl[(size_t)m*5 + b]; M = fmaxf(M, p[b][0]); }
    float S = 0.0f;
    #pragma unroll
    for (int b=0;b<5;b++) S += p[b][1] * expf(p[b][0] - M);
    float ce = logf(S) + M - Lfl[m];
    float bce = bcef(Topol[(size_t)m*3+0]+bt0, (float)is_parent[node])
              + bcef(Topol[(size_t)m*3+1]+bt1, (float)has_sib[node])
              + bcef(Topol[(size_t)m*3+2]+bt2, (float)is_res[node]);
    acc += ce + bce;
  }
  #pragma unroll
  for (int off=32;off>=1;off>>=1) acc += __shfl_xor(acc, off);
  if ((threadIdx.x&63)==0) atomicAdd(&lsum[wvi], acc);
  __syncthreads();
  if (threadIdx.x == 0){
    atomicAdd(loss, (lsum[0]+lsum[1]+lsum[2]+lsum[3]) * INV_N);
  }
}

extern "C" void kernel_launch(void* const* d_in, const int* in_sizes, int n_in,
                              void* d_out, int out_size, void* d_ws, size_t ws_size,
                              hipStream_t stream)
{
  const float* z         = (const float*)d_in[0];
  const float* emb_table = (const float*)d_in[1];
  const float* W_l2h     = (const float*)d_in[2];
  const float* b_l2h     = (const float*)d_in[3];
  const float* W_ih      = (const float*)d_in[4];
  const float* W_hh      = (const float*)d_in[5];
  const float* b_ih      = (const float*)d_in[6];
  const float* b_hh      = (const float*)d_in[7];
  const float* W_ph1     = (const float*)d_in[8];
  const float* b_ph1     = (const float*)d_in[9];
  const float* W_ph2     = (const float*)d_in[10];
  const float* b_ph2     = (const float*)d_in[11];
  const float* W_gate    = (const float*)d_in[12];
  const float* b_gate    = (const float*)d_in[13];
  const float* W_topo    = (const float*)d_in[14];
  const float* b_topo    = (const float*)d_in[15];
  const float* W_pred    = (const float*)d_in[16];
  const float* b_pred    = (const float*)d_in[17];
  const int* features    = (const int*)d_in[18];
  const int* node_level  = (const int*)d_in[19];
  const int* parent_idx  = (const int*)d_in[20];
  const int* sibling_idx = (const int*)d_in[21];
  const int* has_prev    = (const int*)d_in[22];
  const int* tree_id     = (const int*)d_in[23];
  const int* is_parent   = (const int*)d_in[24];
  const int* has_sib     = (const int*)d_in[25];
  const int* is_res      = (const int*)d_in[26];

  char* ws = (char*)d_ws;
  size_t off = 0;
  auto alloc = [&](size_t bytes)->char*{
    char* p = ws + off; off += (bytes + 255) & ~(size_t)255; return p;
  };
  ushort_t* h_state = (ushort_t*)alloc((size_t)NNODES*LATENT*2);   // 33.5 MB
  ushort_t* c_state = (ushort_t*)alloc((size_t)NNODES*LATENT*2);   // 33.5 MB
  ushort_t* A2all   = (ushort_t*)alloc((size_t)NLEV*MAXM*LATENT*2);// 39.3 MB
  ushort_t* PU      = (ushort_t*)alloc((size_t)MAXM*LATENT*2);
  ushort_t* C1      = (ushort_t*)alloc((size_t)MAXM*512*2);
  ushort_t* Cpb     = (ushort_t*)alloc((size_t)MAXM*256*2);
  ushort_t* C3      = (ushort_t*)alloc((size_t)MAXM*1024*2);
  ushort_t* Cpar    = (ushort_t*)alloc((size_t)MAXM*LATENT*2);
  float2v*  LSEp    = (float2v*)alloc((size_t)NLEV*MAXM*5*8);      // 3.1 MB
  float*    Lf      = (float*)alloc((size_t)NLEV*MAXM*4);
  float*    TopoB   = (float*)alloc((size_t)NLEV*MAXM*3*4);
  ushort_t* W1t     = (ushort_t*)alloc((size_t)512*512*2);
  ushort_t* W2t     = (ushort_t*)alloc((size_t)640*256*2);
  ushort_t* W3hh    = (ushort_t*)alloc((size_t)1024*256*2);
  ushort_t* W3ih    = (ushort_t*)alloc((size_t)1024*128*2);
  ushort_t* embbf   = (ushort_t*)alloc((size_t)640*128*2);
  ushort_t* EG      = (ushort_t*)alloc((size_t)640*1024*2);
  float*    root_h  = (float*)alloc((size_t)NTREES*LATENT*4);
  int*      lists   = (int*)alloc((size_t)NLEV*MAXM*4);
  int*      counts  = (int*)alloc(64);
  float*    zpage   = (float*)alloc(1024);
  float*    loss    = (float*)d_out;

  zero_kernel<<<1,256,0,stream>>>(loss, counts, zpage);
  prep_kernel<<<3520,256,0,stream>>>(W_ph1,W_ph2,W_gate,W_topo,W_pred,W_ih,W_hh,emb_table,
                                     W1t,W2t,W3hh,W3ih,embbf);
  eg_gemm<<<dim3(5,8),256,0,stream>>>(embbf, W3ih, EG);
  root_kernel<<<NTREES,LATENT,0,stream>>>(z, W_l2h, b_l2h, root_h);
  init_kernel<<<2048,LATENT,0,stream>>>(node_level, tree_id, root_h, h_state, c_state);
  build_lists_kernel<<<NNODES/256,256,0,stream>>>(node_level, counts, lists);

  for (int lvl=1; lvl<NLEV; lvl++){
    ushort_t* A2 = A2all + (size_t)lvl*MAXM*LATENT;
    k1_gemm<<<dim3(MAXM/64,6),256,0,stream>>>(counts, lvl, lists,
        parent_idx, sibling_idx, has_prev, h_state, (const char*)zpage, W1t, C1, Cpb);
    mid_kernel<<<2048,256,0,stream>>>(counts, lvl, lists, parent_idx, sibling_idx,
        has_prev, h_state, c_state, C1, Cpb, b_ph1, b_ph2, b_gate, A2, PU, Cpar);
    k2_gemm3<<<800,256,0,stream>>>(counts, lvl, PU, W3hh, C3);
    k3_lstm<<<2048,256,0,stream>>>(counts, lvl, lists, C3, Cpar, EG,
        b_ih, b_hh, features, h_state, c_state);
  }

  loss_gemm<<<dim3(250,NLEV-1),256,0,stream>>>(counts, lists, features,
      A2all, W2t, b_pred, LSEp, Lf, TopoB);
  loss_merge<<<dim3(32,NLEV-1),256,0,stream>>>(counts, lists, LSEp, Lf, TopoB,
      b_topo, is_parent, has_sib, is_res, loss);
}